// Round 7
// baseline (5787.326 us; speedup 1.0000x reference)
//
#include <hip/hip_runtime.h>

typedef _Float16 half_t;
typedef _Float16 f16x2 __attribute__((ext_vector_type(2)));
typedef _Float16 f16x8 __attribute__((ext_vector_type(8)));
typedef float f32x4 __attribute__((ext_vector_type(4)));

#define B_SZ 64
#define T_SZ 2048
#define F_SZ 256
#define H_SZ 512
#define O_SZ 128
#define NCH 32      // chunks
#define CH 64       // timesteps per chunk
#define NG 32       // batch groups (2 batches per rec/producer block set)

#if defined(__has_builtin)
#if __has_builtin(__builtin_amdgcn_fdot2)
#define HAS_FDOT2 1
#endif
#if __has_builtin(__builtin_amdgcn_rcpf)
#define HAS_RCPF 1
#endif
#endif
#ifndef HAS_FDOT2
#define HAS_FDOT2 0
#endif
#ifndef HAS_RCPF
#define HAS_RCPF 0
#endif

static __device__ __forceinline__ float fdot2(unsigned int w, unsigned int h, float acc) {
#if HAS_FDOT2
    return __builtin_amdgcn_fdot2(__builtin_bit_cast(f16x2, w), __builtin_bit_cast(f16x2, h), acc, false);
#else
    f16x2 wv = __builtin_bit_cast(f16x2, w);
    f16x2 hv = __builtin_bit_cast(f16x2, h);
    return acc + (float)wv[0] * (float)hv[0] + (float)wv[1] * (float)hv[1];
#endif
}

static __device__ __forceinline__ unsigned int pack_pair(float a, float b) {
    f16x2 p;
    p[0] = (half_t)a;
    p[1] = (half_t)b;
    return __builtin_bit_cast(unsigned int, p);
}

static __device__ __forceinline__ float fast_rcp(float x) {
#if HAS_RCPF
    return __builtin_amdgcn_rcpf(x);
#else
    return 1.0f / x;
#endif
}

// DPP-based in-wave add: x + x[lane ^ pattern], VALU pipe only (no LDS).
// 0x0B1 = quad_perm [1,0,3,2]  (xor 1)
// 0x04E = quad_perm [2,3,0,1]  (xor 2)
// 0x141 = row_half_mirror      (xor 7 within each 8-lane half-row)
template<int CTRL>
static __device__ __forceinline__ float dpp_add(float x) {
    int y = __builtin_amdgcn_mov_dpp(__builtin_bit_cast(int, x), CTRL, 0xF, 0xF, true);
    return x + __builtin_bit_cast(float, y);
}

// Progressive-select butterfly reduce over the 8 K-slice lanes.
// MIRROR (xor7) must run FIRST: its partner lane has inverted low bits, so
// selection is only legal after it. Then xor1 (select bit0), xor2 (select
// bit1), final select bit2. Lane ends with the 8-lane sum of acc[sp].
// 20 DPP + 7 cndmask (vs 24 DPP + 14 cndmask for full-reduce-then-select).
static __device__ __forceinline__ float reduce_sel(float acc[8], bool sb0, bool sb1, bool sb2) {
    float m0 = dpp_add<0x141>(acc[0]);
    float m1 = dpp_add<0x141>(acc[1]);
    float m2 = dpp_add<0x141>(acc[2]);
    float m3 = dpp_add<0x141>(acc[3]);
    float m4 = dpp_add<0x141>(acc[4]);
    float m5 = dpp_add<0x141>(acc[5]);
    float m6 = dpp_add<0x141>(acc[6]);
    float m7 = dpp_add<0x141>(acc[7]);
    float t0 = dpp_add<0x0B1>(m0);
    float t1 = dpp_add<0x0B1>(m1);
    float t2 = dpp_add<0x0B1>(m2);
    float t3 = dpp_add<0x0B1>(m3);
    float t4 = dpp_add<0x0B1>(m4);
    float t5 = dpp_add<0x0B1>(m5);
    float t6 = dpp_add<0x0B1>(m6);
    float t7 = dpp_add<0x0B1>(m7);
    float u0 = sb0 ? t1 : t0;
    float u1 = sb0 ? t3 : t2;
    float u2 = sb0 ? t5 : t4;
    float u3 = sb0 ? t7 : t6;
    u0 = dpp_add<0x04E>(u0);
    u1 = dpp_add<0x04E>(u1);
    u2 = dpp_add<0x04E>(u2);
    u3 = dpp_add<0x04E>(u3);
    float v0 = sb1 ? u1 : u0;
    float v1 = sb1 ? u3 : u2;
    return sb2 ? v1 : v0;
}

// Per-step barrier: LDS-only drain. __syncthreads() would add a vmcnt(0)
// drain of the in-flight xp prefetch / res store every step.
static __device__ __forceinline__ void step_barrier() {
    __builtin_amdgcn_sched_barrier(0);
    asm volatile("s_waitcnt lgkmcnt(0)" ::: "memory");
    __builtin_amdgcn_s_barrier();
    __builtin_amdgcn_sched_barrier(0);
}

// ---------------- prep ----------------

__global__ void cvt_f32_f16(const float* __restrict__ src, half_t* __restrict__ dst, int n) {
    int i = blockIdx.x * 256 + threadIdx.x;
    if (i < n) dst[i] = (half_t)src[i];
}

__global__ void zero_flags(unsigned int* __restrict__ p, int n) {
    int i = blockIdx.x * 256 + threadIdx.x;
    if (i < n) p[i] = 0u;
}

// ---------------- xp0 GEMM (MFMA f16), layer-0 input projection ----------------
template<bool A_F32, int K>
__global__ __launch_bounds__(256) void gemm_xp(const void* __restrict__ Aptr,
                                               const half_t* __restrict__ Bw,
                                               const float* __restrict__ bias1,
                                               const float* __restrict__ bias2,
                                               half_t* __restrict__ Cout)
{
    const int nt   = blockIdx.x & 7;
    const int mt   = blockIdx.x >> 3;
    const int wave = threadIdx.x >> 6;
    const int lane = threadIdx.x & 63;
    const int mrow = mt * 64 + wave * 16 + (lane & 15);
    const int koff = (lane >> 4) * 8;

    f32x4 acc[4];
#pragma unroll
    for (int i = 0; i < 4; i++) acc[i] = (f32x4){0.f, 0.f, 0.f, 0.f};

#pragma unroll 2
    for (int k0 = 0; k0 < K; k0 += 32) {
        f16x8 a;
        if (A_F32) {
            const float* ap = (const float*)Aptr + (size_t)mrow * K + (k0 + koff);
            float4 v0 = ((const float4*)ap)[0];
            float4 v1 = ((const float4*)ap)[1];
            a[0] = (half_t)v0.x; a[1] = (half_t)v0.y; a[2] = (half_t)v0.z; a[3] = (half_t)v0.w;
            a[4] = (half_t)v1.x; a[5] = (half_t)v1.y; a[6] = (half_t)v1.z; a[7] = (half_t)v1.w;
        } else {
            const half_t* ap = (const half_t*)Aptr + (size_t)mrow * K + (k0 + koff);
            a = *(const f16x8*)ap;
        }
#pragma unroll
        for (int cb = 0; cb < 4; cb++) {
            const int col = nt * 64 + cb * 16 + (lane & 15);
            f16x8 bfrag = *(const f16x8*)(Bw + (size_t)col * K + (k0 + koff));
            acc[cb] = __builtin_amdgcn_mfma_f32_16x16x32_f16(a, bfrag, acc[cb], 0, 0, 0);
        }
    }
    const int rbase = mt * 64 + wave * 16 + (lane >> 4) * 4;
#pragma unroll
    for (int cb = 0; cb < 4; cb++) {
        const int col = nt * 64 + cb * 16 + (lane & 15);
        const float bsum = bias1[col] + bias2[col];
#pragma unroll
        for (int r = 0; r < 4; r++) {
            Cout[(size_t)(rbase + r) * H_SZ + col] = (half_t)(acc[cb][r] + bsum);
        }
    }
}

// ---------------- mega-kernel: pipelined 2-layer RNN, 2 batches/block ----------------
// 96 blocks x 512 threads, role = blockIdx.x % 3, group g = blockIdx.x / 3
// owns batches b0 = 2g, b1 = 2g+1:
//  role 0: layer-0 recurrence for BOTH batches on bufA; releases
//          flags0[g][chunk] after each 64-step chunk (agent scope).
//  role 1: xp1 producer: polls flags0, MFMA-GEMMs both batches' res chunk
//          @ W_ih1^T + bias into bufB, releases flags1[g][chunk].
//  role 2: layer-1 recurrence for both batches on bufB; polls flags1;
//          writes hT at t=T-1.
//
// Rec decomposition (intra-wave K-split as round 3): wave s owns output rows
// 64s..64s+63. Lane l = 8q + sp computes rows 64s+8q+{0..7} over K-columns
// 64sp..64sp+63. W_hh pairs 0..23 in registers (192 u32), pairs 24..31 in
// LDS — W is SHARED by both batches, so the 16 ds_read_b128/step are read
// once and consumed twice.
//
// WHY 2 batches: the per-step phases (post-barrier LDS burst -> fdot2 phase
// -> reduce/tanh tail -> barrier) are serialized across all waves — pipe-busy
// sums say ~2700cy but we measure ~3830 (r3) because VALU idles during the
// LDS burst and vice versa. Batch B's fdot2 stream is independent of batch
// A's LDS reads, so within each wave the two streams overlap (plain ILP),
// converting phase-serial time into pipe-parallel time at zero extra W cost.
__global__ __launch_bounds__(512, 2)
void rnn_mega(half_t* bufA, half_t* bufB,
              const float* __restrict__ Whh0, const float* __restrict__ Whh1,
              const half_t* __restrict__ Wih1h,
              const float* __restrict__ h0_0, const float* __restrict__ h0_1,
              const float* __restrict__ b_ih1, const float* __restrict__ b_hh1,
              float* hT,
              unsigned int* flags0, unsigned int* flags1)
{
    __shared__ __align__(16) uint4  wlds[16 * 512];        // 128 KB (W pairs 24..31)
    __shared__ __align__(16) half_t hpad[2][2][8 * 72];    // [batch][parity] h slices

    const int role = blockIdx.x % 3;
    const int g    = blockIdx.x / 3;
    const int b0   = 2 * g;
    const int tid  = threadIdx.x;
    const int l    = tid & 63;
    const int s    = tid >> 6;

    if (role == 1) {
        // ---------- xp1 chunk-GEMM producer (both batches) ----------
        const int w = s, lane = l;
        const int koff = (lane >> 4) * 8;
        for (int chunk = 0; chunk < NCH; chunk++) {
            if (tid == 0) {
                while (__hip_atomic_load(&flags0[g * NCH + chunk], __ATOMIC_ACQUIRE,
                                         __HIP_MEMORY_SCOPE_AGENT) == 0u)
                    __builtin_amdgcn_s_sleep(2);
            }
            __syncthreads();   // all threads gated; acquire-inv done by wave 0
            const int t0 = chunk * CH;

#pragma unroll 1
            for (int bb = 0; bb < 2; bb++) {
                const int bat = b0 + bb;
                f32x4 gac[4][4];
#pragma unroll
                for (int rt = 0; rt < 4; rt++)
#pragma unroll
                    for (int cb = 0; cb < 4; cb++) gac[rt][cb] = (f32x4){0.f, 0.f, 0.f, 0.f};

#pragma unroll 1
                for (int k0 = 0; k0 < H_SZ; k0 += 32) {
                    f16x8 bf[4];
#pragma unroll
                    for (int cb = 0; cb < 4; cb++)
                        bf[cb] = *(const f16x8*)(Wih1h +
                                  (size_t)(64 * w + 16 * cb + (lane & 15)) * H_SZ + k0 + koff);
#pragma unroll
                    for (int rt = 0; rt < 4; rt++) {
                        const f16x8 a = *(const f16x8*)((const half_t*)bufA +
                                  ((size_t)bat * T_SZ + t0 + rt * 16 + (lane & 15)) * H_SZ + k0 + koff);
#pragma unroll
                        for (int cb = 0; cb < 4; cb++)
                            gac[rt][cb] = __builtin_amdgcn_mfma_f32_16x16x32_f16(a, bf[cb], gac[rt][cb], 0, 0, 0);
                    }
                }
#pragma unroll
                for (int rt = 0; rt < 4; rt++) {
                    const int rbase = t0 + rt * 16 + (lane >> 4) * 4;
#pragma unroll
                    for (int cb = 0; cb < 4; cb++) {
                        const int col = 64 * w + 16 * cb + (lane & 15);
                        const float bsum = b_ih1[col] + b_hh1[col];
#pragma unroll
                        for (int r = 0; r < 4; r++)
                            bufB[((size_t)bat * T_SZ + rbase + r) * H_SZ + col] =
                                (half_t)(gac[rt][cb][r] + bsum);
                    }
                }
            }
            __syncthreads();   // drain all waves' bufB stores (vmcnt0 at barrier)
            if (tid == 0)
                __hip_atomic_store(&flags1[g * NCH + chunk], 1u, __ATOMIC_RELEASE,
                                   __HIP_MEMORY_SCOPE_AGENT);
        }
        return;
    }

    // ---------- recurrence (roles 0 and 2), two batches ----------
    const bool L1 = (role == 2);
    const float* Whh = L1 ? Whh1 : Whh0;

    const int q  = l >> 3;    // row-group within wave
    const int sp = l & 7;     // K-slice within wave

    unsigned int wreg[192];   // [pair c][row r] = wreg[c*8+r], pairs 0..23
#pragma unroll
    for (int r = 0; r < 8; r++) {
        const float* wrow = Whh + (size_t)(64 * s + 8 * q + r) * H_SZ + 64 * sp;
#pragma unroll
        for (int c = 0; c < 24; c++)
            wreg[c * 8 + r] = pack_pair(wrow[2 * c], wrow[2 * c + 1]);
    }
#pragma unroll
    for (int p2 = 0; p2 < 8; p2++) {        // pairs 24..31 -> LDS
#pragma unroll
        for (int rh = 0; rh < 2; rh++) {
            unsigned int qv[4];
#pragma unroll
            for (int rr = 0; rr < 4; rr++) {
                const int r = rh * 4 + rr;
                const float* wrow = Whh + (size_t)(64 * s + 8 * q + r) * H_SZ + 64 * sp;
                const int c = 24 + p2;
                qv[rr] = pack_pair(wrow[2 * c], wrow[2 * c + 1]);
            }
            uint4 v;
            v.x = qv[0]; v.y = qv[1]; v.z = qv[2]; v.w = qv[3];
            wlds[(p2 * 2 + rh) * 512 + tid] = v;
        }
    }
    // h0 is a broadcast [H] buffer -> identical for both batches
    {
        const float h0v = (L1 ? h0_1 : h0_0)[tid];
        hpad[0][0][s * 72 + l] = (half_t)h0v;
        hpad[1][0][s * 72 + l] = (half_t)h0v;
    }
    __syncthreads();

    unsigned short* xp16 = (unsigned short*)(L1 ? bufB : bufA);
    const size_t baseA = (size_t)b0 * T_SZ * H_SZ + tid;
    const size_t baseB = baseA + (size_t)T_SZ * H_SZ;

    const bool sb0 = (sp & 1) != 0;
    const bool sb1 = (sp & 2) != 0;
    const bool sb2 = (sp & 4) != 0;

#pragma unroll 1
    for (int chunk = 0; chunk < NCH; chunk++) {
        const int t0 = chunk * CH;
        if (L1) {
            if (tid == 0) {
                while (__hip_atomic_load(&flags1[g * NCH + chunk], __ATOMIC_ACQUIRE,
                                         __HIP_MEMORY_SCOPE_AGENT) == 0u)
                    __builtin_amdgcn_s_sleep(2);
            }
            __syncthreads();
        }
        unsigned short xpA_next = xp16[baseA + (size_t)t0 * H_SZ];
        unsigned short xpB_next = xp16[baseB + (size_t)t0 * H_SZ];

#pragma unroll 1
        for (int tt = 0; tt < CH; tt++) {
            const int t = t0 + tt;
            const int par = tt & 1;
            const unsigned short xpA = xpA_next;
            const unsigned short xpB = xpB_next;
            if (tt + 1 < CH) {
                xpA_next = xp16[baseA + (size_t)(t + 1) * H_SZ];
                xpB_next = xp16[baseB + (size_t)(t + 1) * H_SZ];
            }

            const uint4* hpA = (const uint4*)&hpad[0][par][sp * 72];
            const uint4* hpB = (const uint4*)&hpad[1][par][sp * 72];

            float accA[8], accB[8];
#pragma unroll
            for (int r = 0; r < 8; r++) { accA[r] = 0.f; accB[r] = 0.f; }

#define REGBLK(CC, HV, ACC) { \
                const unsigned int hx0 = (HV).x, hx1 = (HV).y, hx2 = (HV).z, hx3 = (HV).w; \
                _Pragma("unroll") \
                for (int r = 0; r < 8; r++) ACC[r] = fdot2(wreg[((CC) * 4 + 0) * 8 + r], hx0, ACC[r]); \
                _Pragma("unroll") \
                for (int r = 0; r < 8; r++) ACC[r] = fdot2(wreg[((CC) * 4 + 1) * 8 + r], hx1, ACC[r]); \
                _Pragma("unroll") \
                for (int r = 0; r < 8; r++) ACC[r] = fdot2(wreg[((CC) * 4 + 2) * 8 + r], hx2, ACC[r]); \
                _Pragma("unroll") \
                for (int r = 0; r < 8; r++) ACC[r] = fdot2(wreg[((CC) * 4 + 3) * 8 + r], hx3, ACC[r]); }

            // register pairs 0..23: the two batch streams interleave (ILP)
#pragma unroll
            for (int cc = 0; cc < 6; cc++) {
                const uint4 av = hpA[cc];
                const uint4 bv = hpB[cc];
                REGBLK(cc, av, accA)
                REGBLK(cc, bv, accB)
            }

            // LDS pairs 24..31: W read ONCE, consumed by both batches
            const uint4 a6 = hpA[6], a7 = hpA[7];
            const uint4 b6 = hpB[6], b7 = hpB[7];
#define CONSUME(ACC, H2) { \
                ACC[0] = fdot2(wv0.x, (H2), ACC[0]); ACC[1] = fdot2(wv0.y, (H2), ACC[1]); \
                ACC[2] = fdot2(wv0.z, (H2), ACC[2]); ACC[3] = fdot2(wv0.w, (H2), ACC[3]); \
                ACC[4] = fdot2(wv1.x, (H2), ACC[4]); ACC[5] = fdot2(wv1.y, (H2), ACC[5]); \
                ACC[6] = fdot2(wv1.z, (H2), ACC[6]); ACC[7] = fdot2(wv1.w, (H2), ACC[7]); }
#define WSTAGE(P2, H2A, H2B) { \
                const uint4 wv0 = wlds[((P2) * 2 + 0) * 512 + tid]; \
                const uint4 wv1 = wlds[((P2) * 2 + 1) * 512 + tid]; \
                CONSUME(accA, (H2A)) \
                CONSUME(accB, (H2B)) }

            WSTAGE(0, a6.x, b6.x)
            WSTAGE(1, a6.y, b6.y)
            WSTAGE(2, a6.z, b6.z)
            WSTAGE(3, a6.w, b6.w)
            WSTAGE(4, a7.x, b7.x)
            WSTAGE(5, a7.y, b7.y)
            WSTAGE(6, a7.z, b7.z)
            WSTAGE(7, a7.w, b7.w)
#undef WSTAGE
#undef CONSUME
#undef REGBLK

            const float rsA = reduce_sel(accA, sb0, sb1, sb2);
            const float rsB = reduce_sel(accB, sb0, sb1, sb2);

            float yA = (float)__builtin_bit_cast(half_t, xpA) + rsA;
            float yB = (float)__builtin_bit_cast(half_t, xpB) + rsB;
            float eA = __expf(2.0f * yA);
            float eB = __expf(2.0f * yB);
            float hnA = 1.0f - 2.0f * fast_rcp(eA + 1.0f);
            float hnB = 1.0f - 2.0f * fast_rcp(eB + 1.0f);

            hpad[0][par ^ 1][s * 72 + l] = (half_t)hnA;   // next step's h
            hpad[1][par ^ 1][s * 72 + l] = (half_t)hnB;
            if (!L1) {
                xp16[baseA + (size_t)t * H_SZ] = __builtin_bit_cast(unsigned short, (half_t)hnA);
                xp16[baseB + (size_t)t * H_SZ] = __builtin_bit_cast(unsigned short, (half_t)hnB);
            } else if (t == T_SZ - 1) {
                hT[(size_t)b0 * H_SZ + tid]       = hnA;
                hT[(size_t)(b0 + 1) * H_SZ + tid] = hnB;
            }

            step_barrier();    // lgkmcnt(0) + s_barrier: NO vmcnt drain
        }
        if (!L1) {
            __syncthreads();   // real barrier: vmcnt0 drains this chunk's res stores
            if (tid == 0)
                __hip_atomic_store(&flags0[g * NCH + chunk], 1u, __ATOMIC_RELEASE,
                                   __HIP_MEMORY_SCOPE_AGENT);
        }
    }
}

// ---------------- head ----------------
__global__ __launch_bounds__(128) void head_fc(const float* __restrict__ hT,
                                               const float* __restrict__ Wfc,
                                               const float* __restrict__ bfc,
                                               float* __restrict__ out)
{
    __shared__ float hs[H_SZ];
    const int b = blockIdx.x, o = threadIdx.x;
    for (int i = o; i < H_SZ; i += 128) hs[i] = hT[(size_t)b * H_SZ + i];
    __syncthreads();
    const float4* w4 = (const float4*)(Wfc + (size_t)o * H_SZ);
    const float4* h4 = (const float4*)hs;
    float acc = 0.f;
#pragma unroll 4
    for (int k = 0; k < H_SZ / 4; k++) {
        float4 w = w4[k], h = h4[k];
        acc += w.x * h.x + w.y * h.y + w.z * h.z + w.w * h.w;
    }
    out[(size_t)b * O_SZ + o] = acc + bfc[o];
}

// ---------------- launch ----------------

extern "C" void kernel_launch(void* const* d_in, const int* in_sizes, int n_in,
                              void* d_out, int out_size, void* d_ws, size_t ws_size,
                              hipStream_t stream) {
    const float* x     = (const float*)d_in[0];
    const float* W_ih0 = (const float*)d_in[1];
    const float* W_hh0 = (const float*)d_in[2];
    const float* b_ih0 = (const float*)d_in[3];
    const float* b_hh0 = (const float*)d_in[4];
    const float* h0_0  = (const float*)d_in[5];
    const float* W_ih1 = (const float*)d_in[6];
    const float* W_hh1 = (const float*)d_in[7];
    const float* b_ih1 = (const float*)d_in[8];
    const float* b_hh1 = (const float*)d_in[9];
    const float* h0_1  = (const float*)d_in[10];
    const float* W_fc  = (const float*)d_in[11];
    const float* b_fc  = (const float*)d_in[12];

    char* ws = (char*)d_ws;
    size_t off = 0;
    const size_t bufElems = (size_t)B_SZ * T_SZ * H_SZ;          // 67,108,864
    half_t* bufA  = (half_t*)(ws + off); off += bufElems * 2;    // xp0 -> res (in place)
    half_t* bufB  = (half_t*)(ws + off); off += bufElems * 2;    // xp1 (per-chunk producer)
    half_t* Wih0h = (half_t*)(ws + off); off += (size_t)H_SZ * F_SZ * 2;
    half_t* Wih1h = (half_t*)(ws + off); off += (size_t)H_SZ * H_SZ * 2;
    float*  hTbuf = (float*)(ws + off);  off += (size_t)B_SZ * H_SZ * 4;
    const int FLAG_N = NG * NCH;   // 1024
    unsigned int* flags0 = (unsigned int*)(ws + off); off += (size_t)FLAG_N * 4;
    unsigned int* flags1 = (unsigned int*)(ws + off); off += (size_t)FLAG_N * 4;

    const int M = B_SZ * T_SZ;   // 131072

    zero_flags<<<(2 * FLAG_N + 255) / 256, 256, 0, stream>>>(flags0, 2 * FLAG_N);
    cvt_f32_f16<<<(H_SZ * F_SZ + 255) / 256, 256, 0, stream>>>(W_ih0, Wih0h, H_SZ * F_SZ);
    cvt_f32_f16<<<(H_SZ * H_SZ + 255) / 256, 256, 0, stream>>>(W_ih1, Wih1h, H_SZ * H_SZ);

    // xp0 = x @ W_ih0^T + b_ih0 + b_hh0
    gemm_xp<true, F_SZ><<<(M / 64) * 8, 256, 0, stream>>>(x, Wih0h, b_ih0, b_hh0, bufA);

    // pipelined: layer-0 rec + xp1 producer + layer-1 rec, all concurrent;
    // 32 groups x 3 roles = 96 blocks, 2 batches per group.
    rnn_mega<<<96, 512, 0, stream>>>(bufA, bufB, W_hh0, W_hh1, Wih1h,
                                     h0_0, h0_1, b_ih1, b_hh1,
                                     hTbuf, flags0, flags1);

    head_fc<<<B_SZ, 128, 0, stream>>>(hTbuf, W_fc, b_fc, (float*)d_out);
}

// Round 8
// 3529.914 us; speedup vs baseline: 1.6395x; 1.6395x over previous
//
#include <hip/hip_runtime.h>

typedef _Float16 half_t;
typedef _Float16 f16x2 __attribute__((ext_vector_type(2)));
typedef _Float16 f16x8 __attribute__((ext_vector_type(8)));
typedef float f32x4 __attribute__((ext_vector_type(4)));

#define B_SZ 64
#define T_SZ 2048
#define F_SZ 256
#define H_SZ 512
#define O_SZ 128
#define NCH 64      // chunks
#define CH 32       // timesteps per chunk (smaller -> shorter pipeline fill lag)

#if defined(__has_builtin)
#if __has_builtin(__builtin_amdgcn_fdot2)
#define HAS_FDOT2 1
#endif
#if __has_builtin(__builtin_amdgcn_rcpf)
#define HAS_RCPF 1
#endif
#endif
#ifndef HAS_FDOT2
#define HAS_FDOT2 0
#endif
#ifndef HAS_RCPF
#define HAS_RCPF 0
#endif

static __device__ __forceinline__ float fdot2(unsigned int w, unsigned int h, float acc) {
#if HAS_FDOT2
    return __builtin_amdgcn_fdot2(__builtin_bit_cast(f16x2, w), __builtin_bit_cast(f16x2, h), acc, false);
#else
    f16x2 wv = __builtin_bit_cast(f16x2, w);
    f16x2 hv = __builtin_bit_cast(f16x2, h);
    return acc + (float)wv[0] * (float)hv[0] + (float)wv[1] * (float)hv[1];
#endif
}

static __device__ __forceinline__ unsigned int pack_pair(float a, float b) {
    f16x2 p;
    p[0] = (half_t)a;
    p[1] = (half_t)b;
    return __builtin_bit_cast(unsigned int, p);
}

static __device__ __forceinline__ float fast_rcp(float x) {
#if HAS_RCPF
    return __builtin_amdgcn_rcpf(x);
#else
    return 1.0f / x;
#endif
}

// DPP-based in-wave add: x + x[lane ^ pattern], VALU pipe only (no LDS).
// 0x0B1 = quad_perm [1,0,3,2]  (xor 1)
// 0x04E = quad_perm [2,3,0,1]  (xor 2)
// 0x141 = row_half_mirror      (xor 7 within each 8-lane half-row)
template<int CTRL>
static __device__ __forceinline__ float dpp_add(float x) {
    int y = __builtin_amdgcn_mov_dpp(__builtin_bit_cast(int, x), CTRL, 0xF, 0xF, true);
    return x + __builtin_bit_cast(float, y);
}

// Progressive-select butterfly reduce over the 8 K-slice lanes (verified on
// HW in round 7). MIRROR (xor7) must run FIRST: its partner lane has inverted
// low bits, so selection is only legal after it. Then xor1 (select bit0),
// xor2 (select bit1), final select bit2. Lane ends with the 8-lane sum of
// acc[sp]. 20 DPP + 7 cndmask (vs 24 DPP + 14 cndmask full-reduce+select).
static __device__ __forceinline__ float reduce_sel(float acc[8], bool sb0, bool sb1, bool sb2) {
    float m0 = dpp_add<0x141>(acc[0]);
    float m1 = dpp_add<0x141>(acc[1]);
    float m2 = dpp_add<0x141>(acc[2]);
    float m3 = dpp_add<0x141>(acc[3]);
    float m4 = dpp_add<0x141>(acc[4]);
    float m5 = dpp_add<0x141>(acc[5]);
    float m6 = dpp_add<0x141>(acc[6]);
    float m7 = dpp_add<0x141>(acc[7]);
    float t0 = dpp_add<0x0B1>(m0);
    float t1 = dpp_add<0x0B1>(m1);
    float t2 = dpp_add<0x0B1>(m2);
    float t3 = dpp_add<0x0B1>(m3);
    float t4 = dpp_add<0x0B1>(m4);
    float t5 = dpp_add<0x0B1>(m5);
    float t6 = dpp_add<0x0B1>(m6);
    float t7 = dpp_add<0x0B1>(m7);
    float u0 = sb0 ? t1 : t0;
    float u1 = sb0 ? t3 : t2;
    float u2 = sb0 ? t5 : t4;
    float u3 = sb0 ? t7 : t6;
    u0 = dpp_add<0x04E>(u0);
    u1 = dpp_add<0x04E>(u1);
    u2 = dpp_add<0x04E>(u2);
    u3 = dpp_add<0x04E>(u3);
    float v0 = sb1 ? u1 : u0;
    float v1 = sb1 ? u3 : u2;
    return sb2 ? v1 : v0;
}

// Per-step barrier: LDS-only drain. __syncthreads() would add a vmcnt(0)
// drain of the in-flight xp prefetch / res store every step.
static __device__ __forceinline__ void step_barrier() {
    __builtin_amdgcn_sched_barrier(0);
    asm volatile("s_waitcnt lgkmcnt(0)" ::: "memory");
    __builtin_amdgcn_s_barrier();
    __builtin_amdgcn_sched_barrier(0);
}

// ---------------- prep ----------------

__global__ void cvt_f32_f16(const float* __restrict__ src, half_t* __restrict__ dst, int n) {
    int i = blockIdx.x * 256 + threadIdx.x;
    if (i < n) dst[i] = (half_t)src[i];
}

__global__ void zero_flags(unsigned int* __restrict__ p, int n) {
    int i = blockIdx.x * 256 + threadIdx.x;
    if (i < n) p[i] = 0u;
}

// ---------------- xp0 GEMM (MFMA f16), layer-0 input projection ----------------
template<bool A_F32, int K>
__global__ __launch_bounds__(256) void gemm_xp(const void* __restrict__ Aptr,
                                               const half_t* __restrict__ Bw,
                                               const float* __restrict__ bias1,
                                               const float* __restrict__ bias2,
                                               half_t* __restrict__ Cout)
{
    const int nt   = blockIdx.x & 7;
    const int mt   = blockIdx.x >> 3;
    const int wave = threadIdx.x >> 6;
    const int lane = threadIdx.x & 63;
    const int mrow = mt * 64 + wave * 16 + (lane & 15);
    const int koff = (lane >> 4) * 8;

    f32x4 acc[4];
#pragma unroll
    for (int i = 0; i < 4; i++) acc[i] = (f32x4){0.f, 0.f, 0.f, 0.f};

#pragma unroll 2
    for (int k0 = 0; k0 < K; k0 += 32) {
        f16x8 a;
        if (A_F32) {
            const float* ap = (const float*)Aptr + (size_t)mrow * K + (k0 + koff);
            float4 v0 = ((const float4*)ap)[0];
            float4 v1 = ((const float4*)ap)[1];
            a[0] = (half_t)v0.x; a[1] = (half_t)v0.y; a[2] = (half_t)v0.z; a[3] = (half_t)v0.w;
            a[4] = (half_t)v1.x; a[5] = (half_t)v1.y; a[6] = (half_t)v1.z; a[7] = (half_t)v1.w;
        } else {
            const half_t* ap = (const half_t*)Aptr + (size_t)mrow * K + (k0 + koff);
            a = *(const f16x8*)ap;
        }
#pragma unroll
        for (int cb = 0; cb < 4; cb++) {
            const int col = nt * 64 + cb * 16 + (lane & 15);
            f16x8 bfrag = *(const f16x8*)(Bw + (size_t)col * K + (k0 + koff));
            acc[cb] = __builtin_amdgcn_mfma_f32_16x16x32_f16(a, bfrag, acc[cb], 0, 0, 0);
        }
    }
    const int rbase = mt * 64 + wave * 16 + (lane >> 4) * 4;
#pragma unroll
    for (int cb = 0; cb < 4; cb++) {
        const int col = nt * 64 + cb * 16 + (lane & 15);
        const float bsum = bias1[col] + bias2[col];
#pragma unroll
        for (int r = 0; r < 4; r++) {
            Cout[(size_t)(rbase + r) * H_SZ + col] = (half_t)(acc[cb][r] + bsum);
        }
    }
}

// ---------------- mega-kernel: pipelined 2-layer RNN ----------------
// 192 blocks x 512 threads, role = blockIdx.x % 3, b = blockIdx.x / 3:
//  role 0: layer-0 recurrence on bufA (xp0 -> res in place); releases
//          flags0[b][chunk] after each 32-step chunk (agent scope).
//  role 1: xp1 producer: polls flags0, MFMA-GEMMs res chunk @ W_ih1^T + bias
//          into bufB, releases flags1[b][chunk].
//  role 2: layer-1 recurrence on bufB; polls flags1; writes hT at t=T-1.
//
// Rec decomposition (intra-wave K-split): wave s owns output rows 64s..64s+63.
// Lane l = 8q + sp computes rows 64s+8q+{0..7} over K-columns 64sp..64sp+63.
// W_hh pairs 0..25 in registers (208 u32, VGPR+AGPR — fdot2 reads AGPR
// directly), pairs 26..31 stream from LDS (12 ds_read_b128/thread/step).
// Row sums reduced across the 8 sp-lanes with reduce_sel (progressive-select
// butterfly) -> element e = 64s + l = tid. h exchanged cross-wave through a
// parity-double-buffered, pad-swizzled LDS f16 buffer. One lgkm-only barrier
// per step.
//
// This {2 waves/SIMD, 26 reg / 6 LDS pairs} point is the closed optimum of
// the design space: W_hh per CU (512 KB) equals the CU register file, LDS
// capacity forbids >=3 waves/SIMD (17/32 overflow pairs = 272 KB > 160 KB),
// and 1 wave/SIMD exposes latency (round 4: 6270 cy/step). Rounds 4-7
// (more regs / VMEM W / MFMA matvec / dual-batch) all regressed.
__global__ __launch_bounds__(512, 2)
void rnn_mega(half_t* bufA, half_t* bufB,
              const float* __restrict__ Whh0, const float* __restrict__ Whh1,
              const half_t* __restrict__ Wih1h,
              const float* __restrict__ h0_0, const float* __restrict__ h0_1,
              const float* __restrict__ b_ih1, const float* __restrict__ b_hh1,
              float* hT,
              unsigned int* flags0, unsigned int* flags1)
{
    __shared__ __align__(16) uint4 wlds[12 * 512];      // 96 KB (W overflow pairs 26..31)
    __shared__ __align__(16) half_t hpad[2][8 * 72];    // 2.25 KB (h, padded slices)

    const int role = blockIdx.x % 3;
    const int b    = blockIdx.x / 3;
    const int tid  = threadIdx.x;
    const int l    = tid & 63;
    const int s    = tid >> 6;

    if (role == 1) {
        // ---------- xp1 chunk-GEMM producer ----------
        const int w = s, lane = l;
        const int koff = (lane >> 4) * 8;
        for (int chunk = 0; chunk < NCH; chunk++) {
            if (tid == 0) {
                while (__hip_atomic_load(&flags0[b * NCH + chunk], __ATOMIC_ACQUIRE,
                                         __HIP_MEMORY_SCOPE_AGENT) == 0u)
                    __builtin_amdgcn_s_sleep(2);
            }
            __syncthreads();   // all threads gated; acquire-inv done by wave 0
            const int t0 = chunk * CH;

            f32x4 gac[2][4];   // CH=32 -> 2 row-tiles of 16 timesteps
#pragma unroll
            for (int rt = 0; rt < 2; rt++)
#pragma unroll
                for (int cb = 0; cb < 4; cb++) gac[rt][cb] = (f32x4){0.f, 0.f, 0.f, 0.f};

#pragma unroll 1
            for (int k0 = 0; k0 < H_SZ; k0 += 32) {
                f16x8 bf[4];
#pragma unroll
                for (int cb = 0; cb < 4; cb++)
                    bf[cb] = *(const f16x8*)(Wih1h +
                              (size_t)(64 * w + 16 * cb + (lane & 15)) * H_SZ + k0 + koff);
#pragma unroll
                for (int rt = 0; rt < 2; rt++) {
                    const f16x8 a = *(const f16x8*)((const half_t*)bufA +
                              ((size_t)b * T_SZ + t0 + rt * 16 + (lane & 15)) * H_SZ + k0 + koff);
#pragma unroll
                    for (int cb = 0; cb < 4; cb++)
                        gac[rt][cb] = __builtin_amdgcn_mfma_f32_16x16x32_f16(a, bf[cb], gac[rt][cb], 0, 0, 0);
                }
            }
#pragma unroll
            for (int rt = 0; rt < 2; rt++) {
                const int rbase = t0 + rt * 16 + (lane >> 4) * 4;
#pragma unroll
                for (int cb = 0; cb < 4; cb++) {
                    const int col = 64 * w + 16 * cb + (lane & 15);
                    const float bsum = b_ih1[col] + b_hh1[col];
#pragma unroll
                    for (int r = 0; r < 4; r++)
                        bufB[((size_t)b * T_SZ + rbase + r) * H_SZ + col] =
                            (half_t)(gac[rt][cb][r] + bsum);
                }
            }
            __syncthreads();   // drain all waves' bufB stores (vmcnt0 at barrier)
            if (tid == 0)
                __hip_atomic_store(&flags1[b * NCH + chunk], 1u, __ATOMIC_RELEASE,
                                   __HIP_MEMORY_SCOPE_AGENT);
        }
        return;
    }

    // ---------- recurrence (roles 0 and 2) ----------
    const bool L1 = (role == 2);
    const float* Whh = L1 ? Whh1 : Whh0;

    const int q  = l >> 3;    // row-group within wave
    const int sp = l & 7;     // K-slice within wave

    unsigned int wreg[208];   // [pair c][row r] = wreg[c*8+r], pairs 0..25
#pragma unroll
    for (int r = 0; r < 8; r++) {
        const float* wrow = Whh + (size_t)(64 * s + 8 * q + r) * H_SZ + 64 * sp;
#pragma unroll
        for (int c = 0; c < 26; c++)
            wreg[c * 8 + r] = pack_pair(wrow[2 * c], wrow[2 * c + 1]);
    }
#pragma unroll
    for (int p2 = 0; p2 < 6; p2++) {        // pairs 26..31 spill to LDS
#pragma unroll
        for (int rh = 0; rh < 2; rh++) {
            unsigned int qv[4];
#pragma unroll
            for (int rr = 0; rr < 4; rr++) {
                const int r = rh * 4 + rr;
                const float* wrow = Whh + (size_t)(64 * s + 8 * q + r) * H_SZ + 64 * sp;
                const int c = 26 + p2;
                qv[rr] = pack_pair(wrow[2 * c], wrow[2 * c + 1]);
            }
            uint4 v;
            v.x = qv[0]; v.y = qv[1]; v.z = qv[2]; v.w = qv[3];
            wlds[(p2 * 2 + rh) * 512 + tid] = v;
        }
    }
    // h0: thread owns element e = 64s + l -> slice s, offset l
    hpad[0][s * 72 + l] = (half_t)((L1 ? h0_1 : h0_0)[tid]);
    __syncthreads();

    unsigned short* xp16 = (unsigned short*)(L1 ? bufB : bufA);
    const size_t base = (size_t)b * T_SZ * H_SZ + tid;

    // per-lane read base: K-slice sp of each parity buffer (144 B stride,
    // 16B-aligned; the 8 broadcast addresses of each b128 cover disjoint
    // 4-bank groups -> conflict-free)
    const uint4* hp0 = (const uint4*)(&hpad[0][sp * 72]);
    const uint4* hp1 = (const uint4*)(&hpad[1][sp * 72]);
    half_t* hw0 = &hpad[0][s * 72 + l];
    half_t* hw1 = &hpad[1][s * 72 + l];

    const bool sb0 = (sp & 1) != 0;
    const bool sb1 = (sp & 2) != 0;
    const bool sb2 = (sp & 4) != 0;

#pragma unroll 1
    for (int chunk = 0; chunk < NCH; chunk++) {
        const int t0 = chunk * CH;
        if (L1) {
            if (tid == 0) {
                while (__hip_atomic_load(&flags1[b * NCH + chunk], __ATOMIC_ACQUIRE,
                                         __HIP_MEMORY_SCOPE_AGENT) == 0u)
                    __builtin_amdgcn_s_sleep(2);
            }
            __syncthreads();
        }
        unsigned short xpw_next = xp16[base + (size_t)t0 * H_SZ];

#pragma unroll 1
        for (int tt = 0; tt < CH; tt++) {
            const int t = t0 + tt;
            const int par = tt & 1;
            const unsigned short xpw = xpw_next;
            if (tt + 1 < CH) xpw_next = xp16[base + (size_t)(t + 1) * H_SZ];

            float acc[8];
#pragma unroll
            for (int r = 0; r < 8; r++) acc[r] = 0.f;

            const uint4* hp = par ? hp1 : hp0;

            // ---- software-pipelined dot-product schedule ----
            uint4 hc  = hp[0];
            uint4 hA  = hp[6];
            uint4 hB  = hp[7];
            uint4 wv0 = wlds[0 * 512 + tid];
            uint4 wv1 = wlds[1 * 512 + tid];

#define REGBLK(CC, HV) { \
                const unsigned int hx0 = (HV).x, hx1 = (HV).y, hx2 = (HV).z, hx3 = (HV).w; \
                _Pragma("unroll") \
                for (int r = 0; r < 8; r++) acc[r] = fdot2(wreg[((CC) * 4 + 0) * 8 + r], hx0, acc[r]); \
                _Pragma("unroll") \
                for (int r = 0; r < 8; r++) acc[r] = fdot2(wreg[((CC) * 4 + 1) * 8 + r], hx1, acc[r]); \
                _Pragma("unroll") \
                for (int r = 0; r < 8; r++) acc[r] = fdot2(wreg[((CC) * 4 + 2) * 8 + r], hx2, acc[r]); \
                _Pragma("unroll") \
                for (int r = 0; r < 8; r++) acc[r] = fdot2(wreg[((CC) * 4 + 3) * 8 + r], hx3, acc[r]); }
#define CONSUME(H2) { \
                acc[0] = fdot2(wv0.x, (H2), acc[0]); acc[1] = fdot2(wv0.y, (H2), acc[1]); \
                acc[2] = fdot2(wv0.z, (H2), acc[2]); acc[3] = fdot2(wv0.w, (H2), acc[3]); \
                acc[4] = fdot2(wv1.x, (H2), acc[4]); acc[5] = fdot2(wv1.y, (H2), acc[5]); \
                acc[6] = fdot2(wv1.z, (H2), acc[6]); acc[7] = fdot2(wv1.w, (H2), acc[7]); }

            {
                uint4 hn;
                // stage 0: reg pairs 0..3, LDS pair 26
                hn = hp[1];  REGBLK(0, hc)  CONSUME(hA.z)
                wv0 = wlds[2 * 512 + tid];  wv1 = wlds[3 * 512 + tid];  hc = hn;
                // stage 1: reg pairs 4..7, LDS pair 27
                hn = hp[2];  REGBLK(1, hc)  CONSUME(hA.w)
                wv0 = wlds[4 * 512 + tid];  wv1 = wlds[5 * 512 + tid];  hc = hn;
                // stage 2: reg pairs 8..11, LDS pair 28
                hn = hp[3];  REGBLK(2, hc)  CONSUME(hB.x)
                wv0 = wlds[6 * 512 + tid];  wv1 = wlds[7 * 512 + tid];  hc = hn;
                // stage 3: reg pairs 12..15, LDS pair 29
                hn = hp[4];  REGBLK(3, hc)  CONSUME(hB.y)
                wv0 = wlds[8 * 512 + tid];  wv1 = wlds[9 * 512 + tid];  hc = hn;
                // stage 4: reg pairs 16..19, LDS pair 30
                hn = hp[5];  REGBLK(4, hc)  CONSUME(hB.z)
                wv0 = wlds[10 * 512 + tid]; wv1 = wlds[11 * 512 + tid]; hc = hn;
                // stage 5: reg pairs 20..23, LDS pair 31
                REGBLK(5, hc)  CONSUME(hB.w)
                // tail: reg pairs 24,25
                {
                    const unsigned int hx0 = hA.x, hx1 = hA.y;
#pragma unroll
                    for (int r = 0; r < 8; r++) acc[r] = fdot2(wreg[24 * 8 + r], hx0, acc[r]);
#pragma unroll
                    for (int r = 0; r < 8; r++) acc[r] = fdot2(wreg[25 * 8 + r], hx1, acc[r]);
                }
            }
#undef REGBLK
#undef CONSUME

            // in-wave reduction over the 8 K-slice lanes (VALU pipe only)
            const float rsum = reduce_sel(acc, sb0, sb1, sb2);

            float y;
            {
                half_t xv = __builtin_bit_cast(half_t, xpw);
                y = (float)xv + rsum;
            }
            float e   = __expf(2.0f * y);
            float hn2 = 1.0f - 2.0f * fast_rcp(e + 1.0f);

            *(par ? hw0 : hw1) = (half_t)hn2;   // next step's h (parity flip)
            if (!L1)
                xp16[base + (size_t)t * H_SZ] = __builtin_bit_cast(unsigned short, (half_t)hn2);
            else if (t == T_SZ - 1)
                hT[(size_t)b * H_SZ + tid] = hn2;

            step_barrier();    // lgkmcnt(0) + s_barrier: NO vmcnt drain
        }
        if (!L1) {
            __syncthreads();   // real barrier: vmcnt0 drains this chunk's res stores
            if (tid == 0)
                __hip_atomic_store(&flags0[b * NCH + chunk], 1u, __ATOMIC_RELEASE,
                                   __HIP_MEMORY_SCOPE_AGENT);
        }
    }
}

// ---------------- head ----------------
__global__ __launch_bounds__(128) void head_fc(const float* __restrict__ hT,
                                               const float* __restrict__ Wfc,
                                               const float* __restrict__ bfc,
                                               float* __restrict__ out)
{
    __shared__ float hs[H_SZ];
    const int b = blockIdx.x, o = threadIdx.x;
    for (int i = o; i < H_SZ; i += 128) hs[i] = hT[(size_t)b * H_SZ + i];
    __syncthreads();
    const float4* w4 = (const float4*)(Wfc + (size_t)o * H_SZ);
    const float4* h4 = (const float4*)hs;
    float acc = 0.f;
#pragma unroll 4
    for (int k = 0; k < H_SZ / 4; k++) {
        float4 w = w4[k], h = h4[k];
        acc += w.x * h.x + w.y * h.y + w.z * h.z + w.w * h.w;
    }
    out[(size_t)b * O_SZ + o] = acc + bfc[o];
}

// ---------------- launch ----------------

extern "C" void kernel_launch(void* const* d_in, const int* in_sizes, int n_in,
                              void* d_out, int out_size, void* d_ws, size_t ws_size,
                              hipStream_t stream) {
    const float* x     = (const float*)d_in[0];
    const float* W_ih0 = (const float*)d_in[1];
    const float* W_hh0 = (const float*)d_in[2];
    const float* b_ih0 = (const float*)d_in[3];
    const float* b_hh0 = (const float*)d_in[4];
    const float* h0_0  = (const float*)d_in[5];
    const float* W_ih1 = (const float*)d_in[6];
    const float* W_hh1 = (const float*)d_in[7];
    const float* b_ih1 = (const float*)d_in[8];
    const float* b_hh1 = (const float*)d_in[9];
    const float* h0_1  = (const float*)d_in[10];
    const float* W_fc  = (const float*)d_in[11];
    const float* b_fc  = (const float*)d_in[12];

    char* ws = (char*)d_ws;
    size_t off = 0;
    const size_t bufElems = (size_t)B_SZ * T_SZ * H_SZ;          // 67,108,864
    half_t* bufA  = (half_t*)(ws + off); off += bufElems * 2;    // xp0 -> res (in place)
    half_t* bufB  = (half_t*)(ws + off); off += bufElems * 2;    // xp1 (per-chunk producer)
    half_t* Wih0h = (half_t*)(ws + off); off += (size_t)H_SZ * F_SZ * 2;
    half_t* Wih1h = (half_t*)(ws + off); off += (size_t)H_SZ * H_SZ * 2;
    float*  hTbuf = (float*)(ws + off);  off += (size_t)B_SZ * H_SZ * 4;
    const int FLAG_N = B_SZ * NCH;   // 4096
    unsigned int* flags0 = (unsigned int*)(ws + off); off += (size_t)FLAG_N * 4;
    unsigned int* flags1 = (unsigned int*)(ws + off); off += (size_t)FLAG_N * 4;

    const int M = B_SZ * T_SZ;   // 131072

    zero_flags<<<(2 * FLAG_N + 255) / 256, 256, 0, stream>>>(flags0, 2 * FLAG_N);
    cvt_f32_f16<<<(H_SZ * F_SZ + 255) / 256, 256, 0, stream>>>(W_ih0, Wih0h, H_SZ * F_SZ);
    cvt_f32_f16<<<(H_SZ * H_SZ + 255) / 256, 256, 0, stream>>>(W_ih1, Wih1h, H_SZ * H_SZ);

    // xp0 = x @ W_ih0^T + b_ih0 + b_hh0
    gemm_xp<true, F_SZ><<<(M / 64) * 8, 256, 0, stream>>>(x, Wih0h, b_ih0, b_hh0, bufA);

    // pipelined: layer-0 rec + xp1 producer + layer-1 rec, all concurrent
    rnn_mega<<<192, 512, 0, stream>>>(bufA, bufB, W_hh0, W_hh1, Wih1h,
                                      h0_0, h0_1, b_ih1, b_hh1,
                                      hTbuf, flags0, flags1);

    head_fc<<<B_SZ, 128, 0, stream>>>(hTbuf, W_fc, b_fc, (float*)d_out);
}